// Round 11
// baseline (1837.194 us; speedup 1.0000x reference)
//
#include <hip/hip_runtime.h>
#include <hip/hip_bf16.h>

typedef __hip_bfloat16 bf16;
typedef unsigned short u16;

#define N_NODES 100000
#define N_EDGES 1600000
#define F_IN 64
#define N_REL 8
#define N_GRAPH 256
#define N_HEAD 4
#define HC 128          // H*C
#define NBLK_SCAN 391   // ceil(100000/256)

__device__ __forceinline__ float lrelu(float x, float s) { return x >= 0.f ? x : s * x; }
__device__ __forceinline__ unsigned fenc(float f) {
  unsigned b = __float_as_uint(f);
  return (b & 0x80000000u) ? ~b : (b | 0x80000000u);
}
__device__ __forceinline__ float fdec(unsigned u) {
  float v = __uint_as_float((u & 0x80000000u) ? (u & 0x7fffffffu) : ~u);
  return fmaxf(fminf(v, 3e38f), -3e38f);
}
__device__ __forceinline__ float lo_bf(unsigned u) { return __uint_as_float(u << 16); }
__device__ __forceinline__ float hi_bf(unsigned u) { return __uint_as_float(u & 0xFFFF0000u); }
__device__ __forceinline__ bf16 f2bf(float v) { return __float2bfloat16(v); }
__device__ __forceinline__ unsigned f2bfu(float v) {
  unsigned u = __float_as_uint(v);
  return (u + 0x7FFFu + ((u >> 16) & 1u)) >> 16;
}

// dtype-adaptive loads: BF=true -> bf16 array; BF=false -> fp32 array
template<bool BF> __device__ __forceinline__ float ldf(const void* p, size_t i) {
  if (BF) { u16 v = ((const u16*)p)[i]; return __uint_as_float(((unsigned)v) << 16); }
  else    { return ((const float*)p)[i]; }
}
template<bool BF> __device__ __forceinline__ float2 ldf2(const void* p, size_t i) {
  if (BF) { unsigned v = ((const unsigned*)p)[i]; return make_float2(lo_bf(v), hi_bf(v)); }
  else    { return ((const float2*)p)[i]; }
}

// ---- dtype probe ----
__global__ void k_probe(const u16* __restrict__ xr, int* __restrict__ flag) {
  int t = threadIdx.x;
  int c = 0;
  for (int i = t; i < 1024; i += 256) {
    unsigned e = (xr[i] >> 7) & 0xFFu;
    if (e >= 100u && e <= 140u) c++;
  }
  __shared__ int sc[256];
  sc[t] = c;
  __syncthreads();
  for (int s = 128; s; s >>= 1) { if (t < s) sc[t] += sc[t + s]; __syncthreads(); }
  if (t == 0) *flag = (sc[0] >= 800) ? 1 : 0;
}

// ---- GAT node transform: 4 nodes / 128-thread block (w stays in L2, read once per block) ----
template<bool BF>
__device__ __forceinline__ void gat_h_body(const void* x, const void* w, const void* att_s,
                                           const void* att_d, u16* __restrict__ h,
                                           float* __restrict__ a_src, float* __restrict__ a_dst,
                                           int n0, float (*xs)[F_IN]) {
  int tid = threadIdx.x;
  for (int i = tid; i < 4 * F_IN; i += 128)
    xs[i >> 6][i & 63] = ldf<BF>(x, (size_t)(n0 + (i >> 6)) * F_IN + (i & 63));
  __syncthreads();
  int j = tid;  // output channel 0..127
  float acc0 = 0.f, acc1 = 0.f, acc2 = 0.f, acc3 = 0.f;
#pragma unroll
  for (int k = 0; k < F_IN; ++k) {
    float wf = ldf<BF>(w, (size_t)k * HC + j);
    acc0 += xs[0][k] * wf;
    acc1 += xs[1][k] * wf;
    acc2 += xs[2][k] * wf;
    acc3 += xs[3][k] * wf;
  }
  float asj = ldf<BF>(att_s, j), adj = ldf<BF>(att_d, j);
  float accs[4] = {acc0, acc1, acc2, acc3};
#pragma unroll
  for (int q = 0; q < 4; ++q) {
    h[(size_t)(n0 + q) * HC + j] = (u16)f2bfu(accs[q]);
    float ps = accs[q] * asj, pd = accs[q] * adj;
#pragma unroll
    for (int off = 16; off > 0; off >>= 1) {
      ps += __shfl_down(ps, off, 32);
      pd += __shfl_down(pd, off, 32);
    }
    if ((j & 31) == 0) {
      a_src[(n0 + q) * N_HEAD + (j >> 5)] = ps;
      a_dst[(n0 + q) * N_HEAD + (j >> 5)] = pd;
    }
  }
}

// ---- merged: gat_h (blocks 0..24999, 4 nodes each) + hist (blocks 25000..37499) ----
__global__ void k_gath_hist(const void* x, const void* w, const void* att_s, const void* att_d,
                            u16* h, float* a_src, float* a_dst,
                            const int* __restrict__ ei, const int* __restrict__ etype,
                            int* __restrict__ deg, int* __restrict__ cnt, const int* flag) {
  __shared__ float xs[4][F_IN];
  if (blockIdx.x < 25000) {
    if (__builtin_amdgcn_readfirstlane(*flag))
      gat_h_body<true>(x, w, att_s, att_d, h, a_src, a_dst, blockIdx.x * 4, xs);
    else
      gat_h_body<false>(x, w, att_s, att_d, h, a_src, a_dst, blockIdx.x * 4, xs);
  } else {
    int e = (blockIdx.x - 25000) * 128 + threadIdx.x;
    if (e < N_EDGES) {
      int d = ei[N_EDGES + e], t = etype[e];
      atomicAdd(&deg[d], 1);
      atomicAdd(&cnt[d * N_REL + t], 1);
    }
  }
}

// ---- 2-level exclusive scan ----
__global__ void k_scan_a(const int* __restrict__ deg, int* __restrict__ rowptr,
                         int* __restrict__ scanblk) {
  __shared__ int buf[256];
  int tid = threadIdx.x;
  int i = blockIdx.x * 256 + tid;
  int v = (i < N_NODES) ? deg[i] : 0;
  buf[tid] = v;
  __syncthreads();
  for (int st = 1; st < 256; st <<= 1) {
    int t = buf[tid];
    int a = (tid >= st) ? buf[tid - st] : 0;
    __syncthreads();
    buf[tid] = t + a;
    __syncthreads();
  }
  if (i < N_NODES) rowptr[i] = buf[tid] - v;
  if (tid == 255) scanblk[blockIdx.x] = buf[255];
}
__global__ void k_scan_b(int* __restrict__ scanblk) {
  __shared__ int buf[512];
  int tid = threadIdx.x;
  int v = (tid < NBLK_SCAN) ? scanblk[tid] : 0;
  buf[tid] = v;
  __syncthreads();
  for (int st = 1; st < 512; st <<= 1) {
    int t = buf[tid];
    int a = (tid >= st) ? buf[tid - st] : 0;
    __syncthreads();
    buf[tid] = t + a;
    __syncthreads();
  }
  if (tid < NBLK_SCAN) scanblk[tid] = buf[tid] - v;
}
__global__ void k_scan_c(int* __restrict__ rowptr, int* __restrict__ wp,
                         const int* __restrict__ scanblk) {
  int i = blockIdx.x * 256 + threadIdx.x;
  if (i < N_NODES) {
    int val = rowptr[i] + scanblk[blockIdx.x];
    rowptr[i] = val;
    wp[i] = val;
  } else if (i == N_NODES) {
    rowptr[N_NODES] = N_EDGES;
  }
}

// ---- scatter edges into CSR order; store logits (float4) per pos ----
__global__ void k_scatter(const int* __restrict__ ei, const int* __restrict__ etype,
                          const float* __restrict__ a_src, const float* __restrict__ a_dst,
                          int* __restrict__ wp, unsigned* __restrict__ csr,
                          float4* __restrict__ p_logit) {
  int e = blockIdx.x * 256 + threadIdx.x;
  if (e >= N_EDGES) return;
  int sn = ei[e], d = ei[N_EDGES + e], t = etype[e];
  int pos = atomicAdd(&wp[d], 1);
  csr[pos] = (unsigned)sn | ((unsigned)t << 20);
  const float4 as = *(const float4*)&a_src[sn * 4];
  const float4 ad = *(const float4*)&a_dst[d * 4];
  float4 lg;
  lg.x = lrelu(as.x + ad.x, 0.2f);
  lg.y = lrelu(as.y + ad.y, 0.2f);
  lg.z = lrelu(as.z + ad.z, 0.2f);
  lg.w = lrelu(as.w + ad.w, 0.2f);
  p_logit[pos] = lg;
}

// ---- segment softmax stats: m, 1/s per (node, head); 16 nodes/block ----
__global__ void k_msum(const int* __restrict__ rowptr, const float* __restrict__ p_logit,
                       float* __restrict__ m_arr, float* __restrict__ si_arr) {
  int tid = threadIdx.x;
  int n = blockIdx.x * 16 + (tid >> 4);   // grid 6250, exact
  int l16 = tid & 15, head = l16 & 3, slot = l16 >> 2;
  int base = rowptr[n], deg = rowptr[n + 1] - base;
  float m = -1e30f;
  for (int i = slot; i < deg; i += 4) m = fmaxf(m, p_logit[(size_t)(base + i) * 4 + head]);
  m = fmaxf(m, __shfl_xor(m, 4, 64));
  m = fmaxf(m, __shfl_xor(m, 8, 64));
  float s = 0.f;
  for (int i = slot; i < deg; i += 4) s += __expf(p_logit[(size_t)(base + i) * 4 + head] - m);
  s += __shfl_xor(s, 4, 64);
  s += __shfl_xor(s, 8, 64);
  if (slot == 0) {
    m_arr[n * 4 + head] = m;
    si_arr[n * 4 + head] = (deg > 0) ? 1.f / s : 0.f;
  }
}

// ---- GAT aggregate (round-6 structure + fused alpha): 4 nodes/block, uint2, 8 in flight ----
template<bool BF>
__device__ __forceinline__ void gat_agg_body(const int* __restrict__ rowptr,
                                             const unsigned* __restrict__ csr,
                                             const float* __restrict__ lg,
                                             const float* __restrict__ m_arr,
                                             const float* __restrict__ si_arr,
                                             const uint2* __restrict__ hu2, const void* gbias,
                                             const void* d1w, const void* d1b,
                                             const int* __restrict__ batch,
                                             unsigned* __restrict__ gmax, int* __restrict__ npg,
                                             float (*os)[132]) {
  int tid = threadIdx.x;
  int wave = tid >> 6, l = tid & 63;
  int d = blockIdx.x * 4 + wave;  // grid 25000, exact
  int base = rowptr[d];
  int deg = rowptr[d + 1] - base;
  int slot = l >> 5, cl = l & 31;   // lane covers channels 4cl..4cl+3 of edge-slot `slot`
  int head = cl >> 3;
  float m = m_arr[d * 4 + head];
  float si = si_arr[d * 4 + head];
  float a0 = 0.f, a1 = 0.f, a2 = 0.f, a3 = 0.f;
  int i = slot;
  for (; i + 6 < deg; i += 8) {
    unsigned sp0 = csr[base + i],     sp1 = csr[base + i + 2];
    unsigned sp2 = csr[base + i + 4], sp3 = csr[base + i + 6];
    float av0 = __expf(lg[(size_t)(base + i) * 4 + head] - m) * si;
    float av1 = __expf(lg[(size_t)(base + i + 2) * 4 + head] - m) * si;
    float av2 = __expf(lg[(size_t)(base + i + 4) * 4 + head] - m) * si;
    float av3 = __expf(lg[(size_t)(base + i + 6) * 4 + head] - m) * si;
    uint2 h0 = hu2[(size_t)(sp0 & 0xFFFFF) * 32 + cl];
    uint2 h1 = hu2[(size_t)(sp1 & 0xFFFFF) * 32 + cl];
    uint2 h2 = hu2[(size_t)(sp2 & 0xFFFFF) * 32 + cl];
    uint2 h3 = hu2[(size_t)(sp3 & 0xFFFFF) * 32 + cl];
    a0 += lo_bf(h0.x) * av0 + lo_bf(h1.x) * av1 + lo_bf(h2.x) * av2 + lo_bf(h3.x) * av3;
    a1 += hi_bf(h0.x) * av0 + hi_bf(h1.x) * av1 + hi_bf(h2.x) * av2 + hi_bf(h3.x) * av3;
    a2 += lo_bf(h0.y) * av0 + lo_bf(h1.y) * av1 + lo_bf(h2.y) * av2 + lo_bf(h3.y) * av3;
    a3 += hi_bf(h0.y) * av0 + hi_bf(h1.y) * av1 + hi_bf(h2.y) * av2 + hi_bf(h3.y) * av3;
  }
  for (; i < deg; i += 2) {
    unsigned sp = csr[base + i];
    float av = __expf(lg[(size_t)(base + i) * 4 + head] - m) * si;
    uint2 hv = hu2[(size_t)(sp & 0xFFFFF) * 32 + cl];
    a0 += lo_bf(hv.x) * av;
    a1 += hi_bf(hv.x) * av;
    a2 += lo_bf(hv.y) * av;
    a3 += hi_bf(hv.y) * av;
  }
  a0 += __shfl_xor(a0, 32, 64);
  a1 += __shfl_xor(a1, 32, 64);
  a2 += __shfl_xor(a2, 32, 64);
  a3 += __shfl_xor(a3, 32, 64);
  if (slot == 0) {
    os[wave][4 * cl + 0] = lrelu(a0 + ldf<BF>(gbias, 4 * cl + 0), 0.01f);
    os[wave][4 * cl + 1] = lrelu(a1 + ldf<BF>(gbias, 4 * cl + 1), 0.01f);
    os[wave][4 * cl + 2] = lrelu(a2 + ldf<BF>(gbias, 4 * cl + 2), 0.01f);
    os[wave][4 * cl + 3] = lrelu(a3 + ldf<BF>(gbias, 4 * cl + 3), 0.01f);
  }
  __syncthreads();
  if (tid < 64) {
    int node = tid >> 4, out = tid & 15;
    float acc = ldf<BF>(d1b, out);
#pragma unroll
    for (int k = 0; k < HC; ++k) acc += os[node][k] * ldf<BF>(d1w, (size_t)k * 16 + out);
    acc = lrelu(acc, 0.01f);
    atomicMax(&gmax[batch[blockIdx.x * 4 + node] * 16 + out], fenc(acc));
  }
  if (tid < 4) atomicAdd(&npg[batch[blockIdx.x * 4 + tid]], 1);
}
__global__ void k_gat_agg(const int* rowptr, const unsigned* csr, const float* lg,
                          const float* m_arr, const float* si_arr,
                          const u16* h, const void* gbias, const void* d1w, const void* d1b,
                          const int* batch, unsigned* gmax, int* npg, const int* flag) {
  __shared__ float os[4][132];
  if (__builtin_amdgcn_readfirstlane(*flag))
    gat_agg_body<true>(rowptr, csr, lg, m_arr, si_arr, (const uint2*)h, gbias, d1w, d1b,
                       batch, gmax, npg, os);
  else
    gat_agg_body<false>(rowptr, csr, lg, m_arr, si_arr, (const uint2*)h, gbias, d1w, d1b,
                        batch, gmax, npg, os);
}

// ---- RGCN1: xw1[r,n,32] = x[n] @ rw1[r] (8 nodes x 1 rel per 256-block) ----
template<bool BF>
__device__ __forceinline__ void xw1_body(const void* x, const void* rw1, bf16* __restrict__ xw1,
                                         int n0, int r, float (*xs)[F_IN]) {
  int tid = threadIdx.x;
  for (int i = tid; i < 8 * F_IN; i += 256) {
    int nn = n0 + (i >> 6);
    xs[i >> 6][i & 63] = (nn < N_NODES) ? ldf<BF>(x, (size_t)nn * F_IN + (i & 63)) : 0.f;
  }
  __syncthreads();
  int nl = tid >> 5, c = tid & 31;
  int n = n0 + nl;
  float acc = 0.f;
#pragma unroll
  for (int k = 0; k < F_IN; ++k) acc += xs[nl][k] * ldf<BF>(rw1, (size_t)(r * F_IN + k) * 32 + c);
  if (n < N_NODES) xw1[((size_t)r * N_NODES + n) * 32 + c] = f2bf(acc);
}
__global__ void k_xw1(const void* x, const void* rw1, bf16* xw1, const int* flag) {
  __shared__ float xs[8][F_IN];
  int n0 = blockIdx.x * 8, r = blockIdx.y;
  if (__builtin_amdgcn_readfirstlane(*flag)) xw1_body<true>(x, rw1, xw1, n0, r, xs);
  else xw1_body<false>(x, rw1, xw1, n0, r, xs);
}

// ---- RGCN1 gather: 4 nodes/block, 4 edge-slots x 16 lanes x 2ch (u32), 8 in flight ----
template<bool BF>
__device__ __forceinline__ void ragg1_body(const int* __restrict__ rowptr,
                                           const unsigned* __restrict__ csr,
                                           const int* __restrict__ cnt,
                                           const unsigned* __restrict__ xw, const void* x,
                                           const void* root1, const void* rb1,
                                           float* __restrict__ z1,
                                           float (*xs)[F_IN], float (*cinv)[N_REL]) {
  int tid = threadIdx.x;
  int n0 = blockIdx.x * 4;  // grid 25000, exact
  {
    int nn = n0 + (tid >> 6);
    xs[tid >> 6][tid & 63] = ldf<BF>(x, (size_t)nn * F_IN + (tid & 63));
  }
  if (tid < 32) {
    int cv = cnt[(n0 + (tid >> 3)) * N_REL + (tid & 7)];
    cinv[tid >> 3][tid & 7] = (cv > 0) ? 1.f / (float)cv : 0.f;
  }
  __syncthreads();
  int wave = tid >> 6, l = tid & 63;
  int slot = l >> 4, cl = l & 15;   // channels 2cl, 2cl+1
  int n = n0 + wave;
  int base = rowptr[n], deg = rowptr[n + 1] - base;
  float a0 = 0.f, a1 = 0.f;
  int i = slot;
  for (; i + 4 < deg; i += 8) {
    unsigned sp0 = csr[base + i], sp1 = csr[base + i + 4];
    int t0 = sp0 >> 20, t1 = sp1 >> 20;
    unsigned v0 = xw[((size_t)t0 * N_NODES + (sp0 & 0xFFFFF)) * 16 + cl];
    unsigned v1 = xw[((size_t)t1 * N_NODES + (sp1 & 0xFFFFF)) * 16 + cl];
    float c0 = cinv[wave][t0], c1 = cinv[wave][t1];
    a0 += lo_bf(v0) * c0 + lo_bf(v1) * c1;
    a1 += hi_bf(v0) * c0 + hi_bf(v1) * c1;
  }
  if (i < deg) {
    unsigned sp = csr[base + i];
    int t = sp >> 20;
    unsigned v = xw[((size_t)t * N_NODES + (sp & 0xFFFFF)) * 16 + cl];
    float c0 = cinv[wave][t];
    a0 += lo_bf(v) * c0;
    a1 += hi_bf(v) * c0;
  }
#pragma unroll
  for (int kk = 0; kk < 16; ++kk) {
    int k = slot * 16 + kk;
    float xv = xs[wave][k];
    float2 wv = ldf2<BF>(root1, (size_t)k * 16 + cl);
    a0 += xv * wv.x;
    a1 += xv * wv.y;
  }
  a0 += __shfl_xor(a0, 16, 64); a0 += __shfl_xor(a0, 32, 64);
  a1 += __shfl_xor(a1, 16, 64); a1 += __shfl_xor(a1, 32, 64);
  if (slot == 0) {
    z1[(size_t)n * 32 + 2 * cl]     = fmaxf(a0 + ldf<BF>(rb1, 2 * cl), 0.f);
    z1[(size_t)n * 32 + 2 * cl + 1] = fmaxf(a1 + ldf<BF>(rb1, 2 * cl + 1), 0.f);
  }
}
__global__ void k_ragg1(const int* rowptr, const unsigned* csr, const int* cnt,
                        const bf16* xw1, const void* x, const void* root1, const void* rb1,
                        float* z1, const int* flag) {
  __shared__ float xs[4][F_IN];
  __shared__ float cinv[4][N_REL];
  if (__builtin_amdgcn_readfirstlane(*flag))
    ragg1_body<true>(rowptr, csr, cnt, (const unsigned*)xw1, x, root1, rb1, z1, xs, cinv);
  else
    ragg1_body<false>(rowptr, csr, cnt, (const unsigned*)xw1, x, root1, rb1, z1, xs, cinv);
}

// ---- RGCN2: zw2[r,n,16] = z1[n] @ rw2[r] ----
template<bool BF>
__device__ __forceinline__ void zw2_body(const float* __restrict__ z1, const void* rw2,
                                         bf16* __restrict__ zw2, float (*zs)[32]) {
  int tid = threadIdx.x;
  int n0 = blockIdx.x * 16;
  for (int i = tid; i < 16 * 32; i += 256) {
    int nn = n0 + (i >> 5);
    zs[i >> 5][i & 31] = (nn < N_NODES) ? z1[(size_t)nn * 32 + (i & 31)] : 0.f;
  }
  __syncthreads();
  int nl = tid >> 4, c = tid & 15;
  int n = n0 + nl, r = blockIdx.y;
  float acc = 0.f;
#pragma unroll
  for (int k = 0; k < 32; ++k) acc += zs[nl][k] * ldf<BF>(rw2, (size_t)(r * 32 + k) * 16 + c);
  if (n < N_NODES) zw2[((size_t)r * N_NODES + n) * 16 + c] = f2bf(acc);
}
__global__ void k_zw2(const float* z1, const void* rw2, bf16* zw2, const int* flag) {
  __shared__ float zs[16][32];
  if (__builtin_amdgcn_readfirstlane(*flag)) zw2_body<true>(z1, rw2, zw2, zs);
  else zw2_body<false>(z1, rw2, zw2, zs);
}

// ---- RGCN2 gather: 4 nodes/block, 8 edge-slots x 8 lanes x 2ch (u32), 16 in flight ----
template<bool BF>
__device__ __forceinline__ void ragg2_body(const int* __restrict__ rowptr,
                                           const unsigned* __restrict__ csr,
                                           const int* __restrict__ cnt,
                                           const unsigned* __restrict__ zw,
                                           const float* __restrict__ z1, const void* root2,
                                           const void* rb2, const int* __restrict__ batch,
                                           float* __restrict__ gsum,
                                           float (*zs)[33], float (*cinv)[N_REL]) {
  int tid = threadIdx.x;
  int n0 = blockIdx.x * 4;  // grid 25000, exact
  if (tid < 128) {
    int nn = n0 + (tid >> 5);
    zs[tid >> 5][tid & 31] = z1[(size_t)nn * 32 + (tid & 31)];
  }
  if (tid < 32) {
    int cv = cnt[(n0 + (tid >> 3)) * N_REL + (tid & 7)];
    cinv[tid >> 3][tid & 7] = (cv > 0) ? 1.f / (float)cv : 0.f;
  }
  __syncthreads();
  int wave = tid >> 6, l = tid & 63;
  int slot = l >> 3, cl = l & 7;   // channels 2cl, 2cl+1 of 16
  int n = n0 + wave;
  int base = rowptr[n], deg = rowptr[n + 1] - base;
  float a0 = 0.f, a1 = 0.f;
  int i = slot;
  for (; i + 8 < deg; i += 16) {
    unsigned sp0 = csr[base + i], sp1 = csr[base + i + 8];
    int t0 = sp0 >> 20, t1 = sp1 >> 20;
    unsigned v0 = zw[((size_t)t0 * N_NODES + (sp0 & 0xFFFFF)) * 8 + cl];
    unsigned v1 = zw[((size_t)t1 * N_NODES + (sp1 & 0xFFFFF)) * 8 + cl];
    float c0 = cinv[wave][t0], c1 = cinv[wave][t1];
    a0 += lo_bf(v0) * c0 + lo_bf(v1) * c1;
    a1 += hi_bf(v0) * c0 + hi_bf(v1) * c1;
  }
  if (i < deg) {
    unsigned sp = csr[base + i];
    int t = sp >> 20;
    unsigned v = zw[((size_t)t * N_NODES + (sp & 0xFFFFF)) * 8 + cl];
    float c0 = cinv[wave][t];
    a0 += lo_bf(v) * c0;
    a1 += hi_bf(v) * c0;
  }
#pragma unroll
  for (int kk = 0; kk < 4; ++kk) {
    int k = slot * 4 + kk;
    float zv = zs[wave][k];
    float2 wv = ldf2<BF>(root2, (size_t)k * 8 + cl);
    a0 += zv * wv.x;
    a1 += zv * wv.y;
  }
  a0 += __shfl_xor(a0, 8, 64); a0 += __shfl_xor(a0, 16, 64); a0 += __shfl_xor(a0, 32, 64);
  a1 += __shfl_xor(a1, 8, 64); a1 += __shfl_xor(a1, 16, 64); a1 += __shfl_xor(a1, 32, 64);
  if (slot == 0) {
    float z2a = fmaxf(a0 + ldf<BF>(rb2, 2 * cl), 0.f);
    float z2b = fmaxf(a1 + ldf<BF>(rb2, 2 * cl + 1), 0.f);
    int g = batch[n];
    atomicAdd(&gsum[g * 16 + 2 * cl], z2a);
    atomicAdd(&gsum[g * 16 + 2 * cl + 1], z2b);
  }
}
__global__ void k_ragg2(const int* rowptr, const unsigned* csr, const int* cnt,
                        const bf16* zw2, const float* z1, const void* root2, const void* rb2,
                        const int* batch, float* gsum, const int* flag) {
  __shared__ float zs[4][33];
  __shared__ float cinv[4][N_REL];
  if (__builtin_amdgcn_readfirstlane(*flag))
    ragg2_body<true>(rowptr, csr, cnt, (const unsigned*)zw2, z1, root2, rb2, batch, gsum,
                     zs, cinv);
  else
    ragg2_body<false>(rowptr, csr, cnt, (const unsigned*)zw2, z1, root2, rb2, batch, gsum,
                      zs, cinv);
}

// ---- final ----
template<bool BF>
__device__ __forceinline__ void final_body(const unsigned* __restrict__ gmax,
                                           const float* __restrict__ gsum,
                                           const int* __restrict__ npg, const void* dw,
                                           const void* db, void* out) {
  int g = threadIdx.x;
  if (g >= N_GRAPH) return;
  float acc = ldf<BF>(db, 0);
  int np = npg[g]; if (np < 1) np = 1;
  float inv = 1.f / (float)np;
#pragma unroll
  for (int c = 0; c < 16; ++c) {
    acc += fdec(gmax[g * 16 + c]) * ldf<BF>(dw, c);
    acc += (gsum[g * 16 + c] * inv) * ldf<BF>(dw, 16 + c);
  }
  if (BF) ((bf16*)out)[g] = f2bf(acc);
  else ((float*)out)[g] = acc;
}
__global__ void k_final(const unsigned* gmax, const float* gsum, const int* npg,
                        const void* dw, const void* db, void* out, const int* flag) {
  if (__builtin_amdgcn_readfirstlane(*flag)) final_body<true>(gmax, gsum, npg, dw, db, out);
  else final_body<false>(gmax, gsum, npg, dw, db, out);
}

extern "C" void kernel_launch(void* const* d_in, const int* in_sizes, int n_in,
                              void* d_out, int out_size, void* d_ws, size_t ws_size,
                              hipStream_t stream) {
  const void* x        = d_in[0];
  const int*  ei       = (const int*)d_in[1];
  const int*  etype    = (const int*)d_in[2];
  const int*  batch    = (const int*)d_in[3];
  const void* gat_w    = d_in[4];
  const void* att_src  = d_in[5];
  const void* att_dst  = d_in[6];
  const void* gat_bias = d_in[7];
  const void* d1w      = d_in[8];
  const void* d1b      = d_in[9];
  const void* rw1      = d_in[10];
  const void* root1    = d_in[11];
  const void* rb1      = d_in[12];
  const void* rw2      = d_in[13];
  const void* root2    = d_in[14];
  const void* rb2      = d_in[15];
  const void* dw       = d_in[16];
  const void* db       = d_in[17];

  // ---- workspace layout (~129.2 MB) ----
  char* ws = (char*)d_ws;
  const size_t o_h     = 0;           // u16  N*128 (25.6MB)  — GAT h table
  const size_t o_plog  = 25600000;    // f32  E*4   (25.6MB)  — logits (raw; alpha fused in agg)
  const size_t o_xw1   = 51200000;    // bf16 R*N*32 (51.2MB) — RGCN1
  const size_t o_zw2   = 0;           // bf16 R*N*16 (25.6MB) — RGCN2, overlays h (dead)
  const size_t o_asrc  = 102400000;   // f32 N*4 (1.6MB) -> m_arr
  const size_t o_adst  = 104000000;   // f32 N*4 (1.6MB) -> si_arr
  const size_t o_deg   = 105600000;   // i32 N (0.4MB)
  const size_t o_rowp  = 106000000;   // i32 N+1
  const size_t o_wp    = 106400016;   // i32 N
  const size_t o_cnt   = 106800016;   // i32 N*8 (3.2MB)
  const size_t o_csr   = 110000016;   // u32 E (6.4MB)
  const size_t o_z1    = 116400016;   // f32 N*32 (12.8MB)
  const size_t o_sblk  = 129200016;   // i32 NBLK_SCAN
  const size_t o_gmax  = 129201600;   // u32 G*16
  const size_t o_gsum  = 129217984;   // f32 G*16
  const size_t o_npg   = 129234368;   // i32 G
  const size_t o_flag  = 129235392;   // i32
  const size_t total   = 129235396;
  if (ws_size < total) return;

  u16*      h      = (u16*)(ws + o_h);
  float*    plog   = (float*)(ws + o_plog);
  bf16*     xw1    = (bf16*)(ws + o_xw1);
  bf16*     zw2    = (bf16*)(ws + o_zw2);
  float*    a_src  = (float*)(ws + o_asrc);
  float*    a_dst  = (float*)(ws + o_adst);
  int*      deg    = (int*)(ws + o_deg);
  int*      rowptr = (int*)(ws + o_rowp);
  int*      wp     = (int*)(ws + o_wp);
  int*      cnt    = (int*)(ws + o_cnt);
  unsigned* csr    = (unsigned*)(ws + o_csr);
  float*    z1     = (float*)(ws + o_z1);
  int*      sblk   = (int*)(ws + o_sblk);
  unsigned* gmax   = (unsigned*)(ws + o_gmax);
  float*    gsum   = (float*)(ws + o_gsum);
  int*      npg    = (int*)(ws + o_npg);
  int*      flag   = (int*)(ws + o_flag);

  // dtype probe
  k_probe<<<1, 256, 0, stream>>>((const u16*)x, flag);

  // zero-init: deg..cnt contiguous, and gmax/gsum/npg
  hipMemsetAsync(ws + o_deg, 0, o_csr - o_deg, stream);
  hipMemsetAsync(ws + o_gmax, 0, 33792, stream);

  // merged: node transform (4 nodes/block) + edge histogram
  k_gath_hist<<<25000 + 12500, 128, 0, stream>>>(x, gat_w, att_src, att_dst, h,
                                                 a_src, a_dst, ei, etype, deg, cnt, flag);

  // CSR scan + scatter
  k_scan_a<<<NBLK_SCAN, 256, 0, stream>>>(deg, rowptr, sblk);
  k_scan_b<<<1, 512, 0, stream>>>(sblk);
  k_scan_c<<<NBLK_SCAN, 256, 0, stream>>>(rowptr, wp, sblk);
  k_scatter<<<(N_EDGES + 255) / 256, 256, 0, stream>>>(ei, etype, a_src, a_dst, wp, csr,
                                                       (float4*)plog);

  // softmax stats (a_src/a_dst reused as m/si)
  k_msum<<<N_NODES / 16, 256, 0, stream>>>(rowptr, plog, a_src, a_dst);

  // GAT aggregate (alpha fused: exp(lg-m)*si inside the gather loop)
  k_gat_agg<<<N_NODES / 4, 256, 0, stream>>>(rowptr, csr, plog, a_src, a_dst, h, gat_bias,
                                             d1w, d1b, batch, gmax, npg, flag);

  // RGCN layer 1
  k_xw1<<<dim3((N_NODES + 7) / 8, N_REL), 256, 0, stream>>>(x, rw1, xw1, flag);
  k_ragg1<<<N_NODES / 4, 256, 0, stream>>>(rowptr, csr, cnt, xw1, x, root1, rb1, z1, flag);

  // RGCN layer 2 (zw2 overlays h — GAT phase done)
  k_zw2<<<dim3((N_NODES + 15) / 16, N_REL), 256, 0, stream>>>(z1, rw2, zw2, flag);
  k_ragg2<<<N_NODES / 4, 256, 0, stream>>>(rowptr, csr, cnt, zw2, z1, root2, rb2,
                                           batch, gsum, flag);

  // fuse
  k_final<<<1, 256, 0, stream>>>(gmax, gsum, npg, dw, db, d_out, flag);
}

// Round 12
// 1267.716 us; speedup vs baseline: 1.4492x; 1.4492x over previous
//
#include <hip/hip_runtime.h>
#include <hip/hip_bf16.h>

typedef __hip_bfloat16 bf16;
typedef unsigned short u16;

#define N_NODES 100000
#define N_EDGES 1600000
#define F_IN 64
#define N_REL 8
#define N_GRAPH 256
#define N_HEAD 4
#define HC 128          // H*C
#define NBLK_SCAN 391   // ceil(100000/256)

__device__ __forceinline__ float lrelu(float x, float s) { return x >= 0.f ? x : s * x; }
__device__ __forceinline__ unsigned fenc(float f) {
  unsigned b = __float_as_uint(f);
  return (b & 0x80000000u) ? ~b : (b | 0x80000000u);
}
__device__ __forceinline__ float fdec(unsigned u) {
  float v = __uint_as_float((u & 0x80000000u) ? (u & 0x7fffffffu) : ~u);
  return fmaxf(fminf(v, 3e38f), -3e38f);
}
__device__ __forceinline__ float lo_bf(unsigned u) { return __uint_as_float(u << 16); }
__device__ __forceinline__ float hi_bf(unsigned u) { return __uint_as_float(u & 0xFFFF0000u); }
__device__ __forceinline__ bf16 f2bf(float v) { return __float2bfloat16(v); }
__device__ __forceinline__ unsigned f2bfu(float v) {
  unsigned u = __float_as_uint(v);
  return (u + 0x7FFFu + ((u >> 16) & 1u)) >> 16;
}

// dtype-adaptive loads: BF=true -> bf16 array; BF=false -> fp32 array
template<bool BF> __device__ __forceinline__ float ldf(const void* p, size_t i) {
  if (BF) { u16 v = ((const u16*)p)[i]; return __uint_as_float(((unsigned)v) << 16); }
  else    { return ((const float*)p)[i]; }
}
template<bool BF> __device__ __forceinline__ float2 ldf2(const void* p, size_t i) {
  if (BF) { unsigned v = ((const unsigned*)p)[i]; return make_float2(lo_bf(v), hi_bf(v)); }
  else    { return ((const float2*)p)[i]; }
}

// ---- dtype probe ----
__global__ void k_probe(const u16* __restrict__ xr, int* __restrict__ flag) {
  int t = threadIdx.x;
  int c = 0;
  for (int i = t; i < 1024; i += 256) {
    unsigned e = (xr[i] >> 7) & 0xFFu;
    if (e >= 100u && e <= 140u) c++;
  }
  __shared__ int sc[256];
  sc[t] = c;
  __syncthreads();
  for (int s = 128; s; s >>= 1) { if (t < s) sc[t] += sc[t + s]; __syncthreads(); }
  if (t == 0) *flag = (sc[0] >= 800) ? 1 : 0;
}

// ---- GAT node transform body (1 node / 128 threads — the ONLY shape that works;
//      multi-node variants exploded twice: r5, r11) ----
template<bool BF>
__device__ __forceinline__ void gat_h_body(const void* x, const void* w, const void* att_s,
                                           const void* att_d, u16* __restrict__ h,
                                           float* __restrict__ a_src, float* __restrict__ a_dst,
                                           int n, float* xs) {
  int j = threadIdx.x;
  if (j < F_IN) xs[j] = ldf<BF>(x, (size_t)n * F_IN + j);
  __syncthreads();
  float acc = 0.f;
#pragma unroll
  for (int k = 0; k < F_IN; ++k) acc += xs[k] * ldf<BF>(w, (size_t)k * HC + j);
  h[(size_t)n * HC + j] = (u16)f2bfu(acc);
  float ps = acc * ldf<BF>(att_s, j);
  float pd = acc * ldf<BF>(att_d, j);
#pragma unroll
  for (int off = 16; off > 0; off >>= 1) {
    ps += __shfl_down(ps, off, 32);
    pd += __shfl_down(pd, off, 32);
  }
  if ((j & 31) == 0) {
    a_src[n * N_HEAD + (j >> 5)] = ps;
    a_dst[n * N_HEAD + (j >> 5)] = pd;
  }
}

// ---- merged: gat_h (blocks 0..99999) + hist (blocks 100000..112499) ----
__global__ void k_gath_hist(const void* x, const void* w, const void* att_s, const void* att_d,
                            u16* h, float* a_src, float* a_dst,
                            const int* __restrict__ ei, const int* __restrict__ etype,
                            int* __restrict__ deg, int* __restrict__ cnt, const int* flag) {
  __shared__ float xs[F_IN];
  if (blockIdx.x < N_NODES) {
    if (__builtin_amdgcn_readfirstlane(*flag))
      gat_h_body<true>(x, w, att_s, att_d, h, a_src, a_dst, blockIdx.x, xs);
    else
      gat_h_body<false>(x, w, att_s, att_d, h, a_src, a_dst, blockIdx.x, xs);
  } else {
    int e = (blockIdx.x - N_NODES) * 128 + threadIdx.x;
    if (e < N_EDGES) {
      int d = ei[N_EDGES + e], t = etype[e];
      atomicAdd(&deg[d], 1);
      atomicAdd(&cnt[d * N_REL + t], 1);
    }
  }
}

// ---- 2-level exclusive scan ----
__global__ void k_scan_a(const int* __restrict__ deg, int* __restrict__ rowptr,
                         int* __restrict__ scanblk) {
  __shared__ int buf[256];
  int tid = threadIdx.x;
  int i = blockIdx.x * 256 + tid;
  int v = (i < N_NODES) ? deg[i] : 0;
  buf[tid] = v;
  __syncthreads();
  for (int st = 1; st < 256; st <<= 1) {
    int t = buf[tid];
    int a = (tid >= st) ? buf[tid - st] : 0;
    __syncthreads();
    buf[tid] = t + a;
    __syncthreads();
  }
  if (i < N_NODES) rowptr[i] = buf[tid] - v;
  if (tid == 255) scanblk[blockIdx.x] = buf[255];
}
__global__ void k_scan_b(int* __restrict__ scanblk) {
  __shared__ int buf[512];
  int tid = threadIdx.x;
  int v = (tid < NBLK_SCAN) ? scanblk[tid] : 0;
  buf[tid] = v;
  __syncthreads();
  for (int st = 1; st < 512; st <<= 1) {
    int t = buf[tid];
    int a = (tid >= st) ? buf[tid - st] : 0;
    __syncthreads();
    buf[tid] = t + a;
    __syncthreads();
  }
  if (tid < NBLK_SCAN) scanblk[tid] = buf[tid] - v;
}
__global__ void k_scan_c(int* __restrict__ rowptr, int* __restrict__ wp,
                         const int* __restrict__ scanblk) {
  int i = blockIdx.x * 256 + threadIdx.x;
  if (i < N_NODES) {
    int val = rowptr[i] + scanblk[blockIdx.x];
    rowptr[i] = val;
    wp[i] = val;
  } else if (i == N_NODES) {
    rowptr[N_NODES] = N_EDGES;
  }
}

// ---- scatter edges into CSR order; store logits (float4) per pos ----
__global__ void k_scatter(const int* __restrict__ ei, const int* __restrict__ etype,
                          const float* __restrict__ a_src, const float* __restrict__ a_dst,
                          int* __restrict__ wp, unsigned* __restrict__ csr,
                          float4* __restrict__ p_logit) {
  int e = blockIdx.x * 256 + threadIdx.x;
  if (e >= N_EDGES) return;
  int sn = ei[e], d = ei[N_EDGES + e], t = etype[e];
  int pos = atomicAdd(&wp[d], 1);
  csr[pos] = (unsigned)sn | ((unsigned)t << 20);
  const float4 as = *(const float4*)&a_src[sn * 4];
  const float4 ad = *(const float4*)&a_dst[d * 4];
  float4 lg;
  lg.x = lrelu(as.x + ad.x, 0.2f);
  lg.y = lrelu(as.y + ad.y, 0.2f);
  lg.z = lrelu(as.z + ad.z, 0.2f);
  lg.w = lrelu(as.w + ad.w, 0.2f);
  p_logit[pos] = lg;
}

// ---- segment softmax stats: m, 1/s per (node, head); 16 nodes/block ----
__global__ void k_msum(const int* __restrict__ rowptr, const float* __restrict__ p_logit,
                       float* __restrict__ m_arr, float* __restrict__ si_arr) {
  int tid = threadIdx.x;
  int n = blockIdx.x * 16 + (tid >> 4);   // grid 6250, exact
  int l16 = tid & 15, head = l16 & 3, slot = l16 >> 2;
  int base = rowptr[n], deg = rowptr[n + 1] - base;
  float m = -1e30f;
  for (int i = slot; i < deg; i += 4) m = fmaxf(m, p_logit[(size_t)(base + i) * 4 + head]);
  m = fmaxf(m, __shfl_xor(m, 4, 64));
  m = fmaxf(m, __shfl_xor(m, 8, 64));
  float s = 0.f;
  for (int i = slot; i < deg; i += 4) s += __expf(p_logit[(size_t)(base + i) * 4 + head] - m);
  s += __shfl_xor(s, 4, 64);
  s += __shfl_xor(s, 8, 64);
  if (slot == 0) {
    m_arr[n * 4 + head] = m;
    si_arr[n * 4 + head] = (deg > 0) ? 1.f / s : 0.f;
  }
}

// ---- GAT aggregate (round-6 structure + fused alpha): 4 nodes/block, uint2, 8 in flight ----
template<bool BF>
__device__ __forceinline__ void gat_agg_body(const int* __restrict__ rowptr,
                                             const unsigned* __restrict__ csr,
                                             const float* __restrict__ lg,
                                             const float* __restrict__ m_arr,
                                             const float* __restrict__ si_arr,
                                             const uint2* __restrict__ hu2, const void* gbias,
                                             const void* d1w, const void* d1b,
                                             const int* __restrict__ batch,
                                             unsigned* __restrict__ gmax, int* __restrict__ npg,
                                             float (*os)[132]) {
  int tid = threadIdx.x;
  int wave = tid >> 6, l = tid & 63;
  int d = blockIdx.x * 4 + wave;  // grid 25000, exact
  int base = rowptr[d];
  int deg = rowptr[d + 1] - base;
  int slot = l >> 5, cl = l & 31;   // lane covers channels 4cl..4cl+3 of edge-slot `slot`
  int head = cl >> 3;
  float m = m_arr[d * 4 + head];
  float si = si_arr[d * 4 + head];
  float a0 = 0.f, a1 = 0.f, a2 = 0.f, a3 = 0.f;
  int i = slot;
  for (; i + 6 < deg; i += 8) {
    unsigned sp0 = csr[base + i],     sp1 = csr[base + i + 2];
    unsigned sp2 = csr[base + i + 4], sp3 = csr[base + i + 6];
    float av0 = __expf(lg[(size_t)(base + i) * 4 + head] - m) * si;
    float av1 = __expf(lg[(size_t)(base + i + 2) * 4 + head] - m) * si;
    float av2 = __expf(lg[(size_t)(base + i + 4) * 4 + head] - m) * si;
    float av3 = __expf(lg[(size_t)(base + i + 6) * 4 + head] - m) * si;
    uint2 h0 = hu2[(size_t)(sp0 & 0xFFFFF) * 32 + cl];
    uint2 h1 = hu2[(size_t)(sp1 & 0xFFFFF) * 32 + cl];
    uint2 h2 = hu2[(size_t)(sp2 & 0xFFFFF) * 32 + cl];
    uint2 h3 = hu2[(size_t)(sp3 & 0xFFFFF) * 32 + cl];
    a0 += lo_bf(h0.x) * av0 + lo_bf(h1.x) * av1 + lo_bf(h2.x) * av2 + lo_bf(h3.x) * av3;
    a1 += hi_bf(h0.x) * av0 + hi_bf(h1.x) * av1 + hi_bf(h2.x) * av2 + hi_bf(h3.x) * av3;
    a2 += lo_bf(h0.y) * av0 + lo_bf(h1.y) * av1 + lo_bf(h2.y) * av2 + lo_bf(h3.y) * av3;
    a3 += hi_bf(h0.y) * av0 + hi_bf(h1.y) * av1 + hi_bf(h2.y) * av2 + hi_bf(h3.y) * av3;
  }
  for (; i < deg; i += 2) {
    unsigned sp = csr[base + i];
    float av = __expf(lg[(size_t)(base + i) * 4 + head] - m) * si;
    uint2 hv = hu2[(size_t)(sp & 0xFFFFF) * 32 + cl];
    a0 += lo_bf(hv.x) * av;
    a1 += hi_bf(hv.x) * av;
    a2 += lo_bf(hv.y) * av;
    a3 += hi_bf(hv.y) * av;
  }
  a0 += __shfl_xor(a0, 32, 64);
  a1 += __shfl_xor(a1, 32, 64);
  a2 += __shfl_xor(a2, 32, 64);
  a3 += __shfl_xor(a3, 32, 64);
  if (slot == 0) {
    os[wave][4 * cl + 0] = lrelu(a0 + ldf<BF>(gbias, 4 * cl + 0), 0.01f);
    os[wave][4 * cl + 1] = lrelu(a1 + ldf<BF>(gbias, 4 * cl + 1), 0.01f);
    os[wave][4 * cl + 2] = lrelu(a2 + ldf<BF>(gbias, 4 * cl + 2), 0.01f);
    os[wave][4 * cl + 3] = lrelu(a3 + ldf<BF>(gbias, 4 * cl + 3), 0.01f);
  }
  __syncthreads();
  if (tid < 64) {
    int node = tid >> 4, out = tid & 15;
    float acc = ldf<BF>(d1b, out);
#pragma unroll
    for (int k = 0; k < HC; ++k) acc += os[node][k] * ldf<BF>(d1w, (size_t)k * 16 + out);
    acc = lrelu(acc, 0.01f);
    atomicMax(&gmax[batch[blockIdx.x * 4 + node] * 16 + out], fenc(acc));
  }
  if (tid < 4) atomicAdd(&npg[batch[blockIdx.x * 4 + tid]], 1);
}
__global__ void k_gat_agg(const int* rowptr, const unsigned* csr, const float* lg,
                          const float* m_arr, const float* si_arr,
                          const u16* h, const void* gbias, const void* d1w, const void* d1b,
                          const int* batch, unsigned* gmax, int* npg, const int* flag) {
  __shared__ float os[4][132];
  if (__builtin_amdgcn_readfirstlane(*flag))
    gat_agg_body<true>(rowptr, csr, lg, m_arr, si_arr, (const uint2*)h, gbias, d1w, d1b,
                       batch, gmax, npg, os);
  else
    gat_agg_body<false>(rowptr, csr, lg, m_arr, si_arr, (const uint2*)h, gbias, d1w, d1b,
                        batch, gmax, npg, os);
}

// ---- RGCN1: xw1[r,n,32] = x[n] @ rw1[r] (8 nodes x 1 rel per 256-block) ----
template<bool BF>
__device__ __forceinline__ void xw1_body(const void* x, const void* rw1, bf16* __restrict__ xw1,
                                         int n0, int r, float (*xs)[F_IN]) {
  int tid = threadIdx.x;
  for (int i = tid; i < 8 * F_IN; i += 256) {
    int nn = n0 + (i >> 6);
    xs[i >> 6][i & 63] = (nn < N_NODES) ? ldf<BF>(x, (size_t)nn * F_IN + (i & 63)) : 0.f;
  }
  __syncthreads();
  int nl = tid >> 5, c = tid & 31;
  int n = n0 + nl;
  float acc = 0.f;
#pragma unroll
  for (int k = 0; k < F_IN; ++k) acc += xs[nl][k] * ldf<BF>(rw1, (size_t)(r * F_IN + k) * 32 + c);
  if (n < N_NODES) xw1[((size_t)r * N_NODES + n) * 32 + c] = f2bf(acc);
}
__global__ void k_xw1(const void* x, const void* rw1, bf16* xw1, const int* flag) {
  __shared__ float xs[8][F_IN];
  int n0 = blockIdx.x * 8, r = blockIdx.y;
  if (__builtin_amdgcn_readfirstlane(*flag)) xw1_body<true>(x, rw1, xw1, n0, r, xs);
  else xw1_body<false>(x, rw1, xw1, n0, r, xs);
}

// ---- RGCN1 gather: 4 nodes/block, 4 edge-slots x 16 lanes x 2ch (u32), 8 in flight ----
template<bool BF>
__device__ __forceinline__ void ragg1_body(const int* __restrict__ rowptr,
                                           const unsigned* __restrict__ csr,
                                           const int* __restrict__ cnt,
                                           const unsigned* __restrict__ xw, const void* x,
                                           const void* root1, const void* rb1,
                                           float* __restrict__ z1,
                                           float (*xs)[F_IN], float (*cinv)[N_REL]) {
  int tid = threadIdx.x;
  int n0 = blockIdx.x * 4;  // grid 25000, exact
  {
    int nn = n0 + (tid >> 6);
    xs[tid >> 6][tid & 63] = ldf<BF>(x, (size_t)nn * F_IN + (tid & 63));
  }
  if (tid < 32) {
    int cv = cnt[(n0 + (tid >> 3)) * N_REL + (tid & 7)];
    cinv[tid >> 3][tid & 7] = (cv > 0) ? 1.f / (float)cv : 0.f;
  }
  __syncthreads();
  int wave = tid >> 6, l = tid & 63;
  int slot = l >> 4, cl = l & 15;   // channels 2cl, 2cl+1
  int n = n0 + wave;
  int base = rowptr[n], deg = rowptr[n + 1] - base;
  float a0 = 0.f, a1 = 0.f;
  int i = slot;
  for (; i + 4 < deg; i += 8) {
    unsigned sp0 = csr[base + i], sp1 = csr[base + i + 4];
    int t0 = sp0 >> 20, t1 = sp1 >> 20;
    unsigned v0 = xw[((size_t)t0 * N_NODES + (sp0 & 0xFFFFF)) * 16 + cl];
    unsigned v1 = xw[((size_t)t1 * N_NODES + (sp1 & 0xFFFFF)) * 16 + cl];
    float c0 = cinv[wave][t0], c1 = cinv[wave][t1];
    a0 += lo_bf(v0) * c0 + lo_bf(v1) * c1;
    a1 += hi_bf(v0) * c0 + hi_bf(v1) * c1;
  }
  if (i < deg) {
    unsigned sp = csr[base + i];
    int t = sp >> 20;
    unsigned v = xw[((size_t)t * N_NODES + (sp & 0xFFFFF)) * 16 + cl];
    float c0 = cinv[wave][t];
    a0 += lo_bf(v) * c0;
    a1 += hi_bf(v) * c0;
  }
#pragma unroll
  for (int kk = 0; kk < 16; ++kk) {
    int k = slot * 16 + kk;
    float xv = xs[wave][k];
    float2 wv = ldf2<BF>(root1, (size_t)k * 16 + cl);
    a0 += xv * wv.x;
    a1 += xv * wv.y;
  }
  a0 += __shfl_xor(a0, 16, 64); a0 += __shfl_xor(a0, 32, 64);
  a1 += __shfl_xor(a1, 16, 64); a1 += __shfl_xor(a1, 32, 64);
  if (slot == 0) {
    z1[(size_t)n * 32 + 2 * cl]     = fmaxf(a0 + ldf<BF>(rb1, 2 * cl), 0.f);
    z1[(size_t)n * 32 + 2 * cl + 1] = fmaxf(a1 + ldf<BF>(rb1, 2 * cl + 1), 0.f);
  }
}
__global__ void k_ragg1(const int* rowptr, const unsigned* csr, const int* cnt,
                        const bf16* xw1, const void* x, const void* root1, const void* rb1,
                        float* z1, const int* flag) {
  __shared__ float xs[4][F_IN];
  __shared__ float cinv[4][N_REL];
  if (__builtin_amdgcn_readfirstlane(*flag))
    ragg1_body<true>(rowptr, csr, cnt, (const unsigned*)xw1, x, root1, rb1, z1, xs, cinv);
  else
    ragg1_body<false>(rowptr, csr, cnt, (const unsigned*)xw1, x, root1, rb1, z1, xs, cinv);
}

// ---- RGCN2: zw2[r,n,16] = z1[n] @ rw2[r] ----
template<bool BF>
__device__ __forceinline__ void zw2_body(const float* __restrict__ z1, const void* rw2,
                                         bf16* __restrict__ zw2, float (*zs)[32]) {
  int tid = threadIdx.x;
  int n0 = blockIdx.x * 16;
  for (int i = tid; i < 16 * 32; i += 256) {
    int nn = n0 + (i >> 5);
    zs[i >> 5][i & 31] = (nn < N_NODES) ? z1[(size_t)nn * 32 + (i & 31)] : 0.f;
  }
  __syncthreads();
  int nl = tid >> 4, c = tid & 15;
  int n = n0 + nl, r = blockIdx.y;
  float acc = 0.f;
#pragma unroll
  for (int k = 0; k < 32; ++k) acc += zs[nl][k] * ldf<BF>(rw2, (size_t)(r * 32 + k) * 16 + c);
  if (n < N_NODES) zw2[((size_t)r * N_NODES + n) * 16 + c] = f2bf(acc);
}
__global__ void k_zw2(const float* z1, const void* rw2, bf16* zw2, const int* flag) {
  __shared__ float zs[16][32];
  if (__builtin_amdgcn_readfirstlane(*flag)) zw2_body<true>(z1, rw2, zw2, zs);
  else zw2_body<false>(z1, rw2, zw2, zs);
}

// ---- RGCN2 gather: 4 nodes/block, 8 edge-slots x 8 lanes x 2ch (u32), 16 in flight ----
template<bool BF>
__device__ __forceinline__ void ragg2_body(const int* __restrict__ rowptr,
                                           const unsigned* __restrict__ csr,
                                           const int* __restrict__ cnt,
                                           const unsigned* __restrict__ zw,
                                           const float* __restrict__ z1, const void* root2,
                                           const void* rb2, const int* __restrict__ batch,
                                           float* __restrict__ gsum,
                                           float (*zs)[33], float (*cinv)[N_REL]) {
  int tid = threadIdx.x;
  int n0 = blockIdx.x * 4;  // grid 25000, exact
  if (tid < 128) {
    int nn = n0 + (tid >> 5);
    zs[tid >> 5][tid & 31] = z1[(size_t)nn * 32 + (tid & 31)];
  }
  if (tid < 32) {
    int cv = cnt[(n0 + (tid >> 3)) * N_REL + (tid & 7)];
    cinv[tid >> 3][tid & 7] = (cv > 0) ? 1.f / (float)cv : 0.f;
  }
  __syncthreads();
  int wave = tid >> 6, l = tid & 63;
  int slot = l >> 3, cl = l & 7;   // channels 2cl, 2cl+1 of 16
  int n = n0 + wave;
  int base = rowptr[n], deg = rowptr[n + 1] - base;
  float a0 = 0.f, a1 = 0.f;
  int i = slot;
  for (; i + 8 < deg; i += 16) {
    unsigned sp0 = csr[base + i], sp1 = csr[base + i + 8];
    int t0 = sp0 >> 20, t1 = sp1 >> 20;
    unsigned v0 = zw[((size_t)t0 * N_NODES + (sp0 & 0xFFFFF)) * 8 + cl];
    unsigned v1 = zw[((size_t)t1 * N_NODES + (sp1 & 0xFFFFF)) * 8 + cl];
    float c0 = cinv[wave][t0], c1 = cinv[wave][t1];
    a0 += lo_bf(v0) * c0 + lo_bf(v1) * c1;
    a1 += hi_bf(v0) * c0 + hi_bf(v1) * c1;
  }
  if (i < deg) {
    unsigned sp = csr[base + i];
    int t = sp >> 20;
    unsigned v = zw[((size_t)t * N_NODES + (sp & 0xFFFFF)) * 8 + cl];
    float c0 = cinv[wave][t];
    a0 += lo_bf(v) * c0;
    a1 += hi_bf(v) * c0;
  }
#pragma unroll
  for (int kk = 0; kk < 4; ++kk) {
    int k = slot * 4 + kk;
    float zv = zs[wave][k];
    float2 wv = ldf2<BF>(root2, (size_t)k * 8 + cl);
    a0 += zv * wv.x;
    a1 += zv * wv.y;
  }
  a0 += __shfl_xor(a0, 8, 64); a0 += __shfl_xor(a0, 16, 64); a0 += __shfl_xor(a0, 32, 64);
  a1 += __shfl_xor(a1, 8, 64); a1 += __shfl_xor(a1, 16, 64); a1 += __shfl_xor(a1, 32, 64);
  if (slot == 0) {
    float z2a = fmaxf(a0 + ldf<BF>(rb2, 2 * cl), 0.f);
    float z2b = fmaxf(a1 + ldf<BF>(rb2, 2 * cl + 1), 0.f);
    int g = batch[n];
    atomicAdd(&gsum[g * 16 + 2 * cl], z2a);
    atomicAdd(&gsum[g * 16 + 2 * cl + 1], z2b);
  }
}
__global__ void k_ragg2(const int* rowptr, const unsigned* csr, const int* cnt,
                        const bf16* zw2, const float* z1, const void* root2, const void* rb2,
                        const int* batch, float* gsum, const int* flag) {
  __shared__ float zs[4][33];
  __shared__ float cinv[4][N_REL];
  if (__builtin_amdgcn_readfirstlane(*flag))
    ragg2_body<true>(rowptr, csr, cnt, (const unsigned*)zw2, z1, root2, rb2, batch, gsum,
                     zs, cinv);
  else
    ragg2_body<false>(rowptr, csr, cnt, (const unsigned*)zw2, z1, root2, rb2, batch, gsum,
                      zs, cinv);
}

// ---- final ----
template<bool BF>
__device__ __forceinline__ void final_body(const unsigned* __restrict__ gmax,
                                           const float* __restrict__ gsum,
                                           const int* __restrict__ npg, const void* dw,
                                           const void* db, void* out) {
  int g = threadIdx.x;
  if (g >= N_GRAPH) return;
  float acc = ldf<BF>(db, 0);
  int np = npg[g]; if (np < 1) np = 1;
  float inv = 1.f / (float)np;
#pragma unroll
  for (int c = 0; c < 16; ++c) {
    acc += fdec(gmax[g * 16 + c]) * ldf<BF>(dw, c);
    acc += (gsum[g * 16 + c] * inv) * ldf<BF>(dw, 16 + c);
  }
  if (BF) ((bf16*)out)[g] = f2bf(acc);
  else ((float*)out)[g] = acc;
}
__global__ void k_final(const unsigned* gmax, const float* gsum, const int* npg,
                        const void* dw, const void* db, void* out, const int* flag) {
  if (__builtin_amdgcn_readfirstlane(*flag)) final_body<true>(gmax, gsum, npg, dw, db, out);
  else final_body<false>(gmax, gsum, npg, dw, db, out);
}

extern "C" void kernel_launch(void* const* d_in, const int* in_sizes, int n_in,
                              void* d_out, int out_size, void* d_ws, size_t ws_size,
                              hipStream_t stream) {
  const void* x        = d_in[0];
  const int*  ei       = (const int*)d_in[1];
  const int*  etype    = (const int*)d_in[2];
  const int*  batch    = (const int*)d_in[3];
  const void* gat_w    = d_in[4];
  const void* att_src  = d_in[5];
  const void* att_dst  = d_in[6];
  const void* gat_bias = d_in[7];
  const void* d1w      = d_in[8];
  const void* d1b      = d_in[9];
  const void* rw1      = d_in[10];
  const void* root1    = d_in[11];
  const void* rb1      = d_in[12];
  const void* rw2      = d_in[13];
  const void* root2    = d_in[14];
  const void* rb2      = d_in[15];
  const void* dw       = d_in[16];
  const void* db       = d_in[17];

  // ---- workspace layout (~129.2 MB) ----
  char* ws = (char*)d_ws;
  const size_t o_h     = 0;           // u16  N*128 (25.6MB)  — GAT h table
  const size_t o_plog  = 25600000;    // f32  E*4   (25.6MB)  — logits (raw; alpha fused in agg)
  const size_t o_xw1   = 51200000;    // bf16 R*N*32 (51.2MB) — RGCN1
  const size_t o_zw2   = 0;           // bf16 R*N*16 (25.6MB) — RGCN2, overlays h (dead)
  const size_t o_asrc  = 102400000;   // f32 N*4 (1.6MB) -> m_arr
  const size_t o_adst  = 104000000;   // f32 N*4 (1.6MB) -> si_arr
  const size_t o_deg   = 105600000;   // i32 N (0.4MB)
  const size_t o_rowp  = 106000000;   // i32 N+1
  const size_t o_wp    = 106400016;   // i32 N
  const size_t o_cnt   = 106800016;   // i32 N*8 (3.2MB)
  const size_t o_csr   = 110000016;   // u32 E (6.4MB)
  const size_t o_z1    = 116400016;   // f32 N*32 (12.8MB)
  const size_t o_sblk  = 129200016;   // i32 NBLK_SCAN
  const size_t o_gmax  = 129201600;   // u32 G*16
  const size_t o_gsum  = 129217984;   // f32 G*16
  const size_t o_npg   = 129234368;   // i32 G
  const size_t o_flag  = 129235392;   // i32
  const size_t total   = 129235396;
  if (ws_size < total) return;

  u16*      h      = (u16*)(ws + o_h);
  float*    plog   = (float*)(ws + o_plog);
  bf16*     xw1    = (bf16*)(ws + o_xw1);
  bf16*     zw2    = (bf16*)(ws + o_zw2);
  float*    a_src  = (float*)(ws + o_asrc);
  float*    a_dst  = (float*)(ws + o_adst);
  int*      deg    = (int*)(ws + o_deg);
  int*      rowptr = (int*)(ws + o_rowp);
  int*      wp     = (int*)(ws + o_wp);
  int*      cnt    = (int*)(ws + o_cnt);
  unsigned* csr    = (unsigned*)(ws + o_csr);
  float*    z1     = (float*)(ws + o_z1);
  int*      sblk   = (int*)(ws + o_sblk);
  unsigned* gmax   = (unsigned*)(ws + o_gmax);
  float*    gsum   = (float*)(ws + o_gsum);
  int*      npg    = (int*)(ws + o_npg);
  int*      flag   = (int*)(ws + o_flag);

  // dtype probe
  k_probe<<<1, 256, 0, stream>>>((const u16*)x, flag);

  // zero-init: deg..cnt contiguous, and gmax/gsum/npg
  hipMemsetAsync(ws + o_deg, 0, o_csr - o_deg, stream);
  hipMemsetAsync(ws + o_gmax, 0, 33792, stream);

  // merged: node transform (1 node/128-thread block — proven shape) + edge histogram
  k_gath_hist<<<N_NODES + 12500, 128, 0, stream>>>(x, gat_w, att_src, att_dst, h,
                                                   a_src, a_dst, ei, etype, deg, cnt, flag);

  // CSR scan + scatter
  k_scan_a<<<NBLK_SCAN, 256, 0, stream>>>(deg, rowptr, sblk);
  k_scan_b<<<1, 512, 0, stream>>>(sblk);
  k_scan_c<<<NBLK_SCAN, 256, 0, stream>>>(rowptr, wp, sblk);
  k_scatter<<<(N_EDGES + 255) / 256, 256, 0, stream>>>(ei, etype, a_src, a_dst, wp, csr,
                                                       (float4*)plog);

  // softmax stats (a_src/a_dst reused as m/si)
  k_msum<<<N_NODES / 16, 256, 0, stream>>>(rowptr, plog, a_src, a_dst);

  // GAT aggregate (alpha fused: exp(lg-m)*si inside the gather loop)
  k_gat_agg<<<N_NODES / 4, 256, 0, stream>>>(rowptr, csr, plog, a_src, a_dst, h, gat_bias,
                                             d1w, d1b, batch, gmax, npg, flag);

  // RGCN layer 1
  k_xw1<<<dim3((N_NODES + 7) / 8, N_REL), 256, 0, stream>>>(x, rw1, xw1, flag);
  k_ragg1<<<N_NODES / 4, 256, 0, stream>>>(rowptr, csr, cnt, xw1, x, root1, rb1, z1, flag);

  // RGCN layer 2 (zw2 overlays h — GAT phase done)
  k_zw2<<<dim3((N_NODES + 15) / 16, N_REL), 256, 0, stream>>>(z1, rw2, zw2, flag);
  k_ragg2<<<N_NODES / 4, 256, 0, stream>>>(rowptr, csr, cnt, zw2, z1, root2, rb2,
                                           batch, gsum, flag);

  // fuse
  k_final<<<1, 256, 0, stream>>>(gmax, gsum, npg, dw, db, d_out, flag);
}